// Round 10
// baseline (95.219 us; speedup 1.0000x reference)
//
#include <hip/hip_runtime.h>

#define GRIDN 256
#define NBINS 1024                // 8 x 8 x 16 bins of 32x32x16 cells
#define CAP 3072                  // slots per bin (interior mean ~2370, sigma ~49)
#define CURSOR_STRIDE 16          // one cursor per 64B line
#define FKEYS 256                 // fine keys: 8x8x4 sub-bins of 4x4x4 cells, z fastest

// ---------- shared helpers ----------

__device__ __forceinline__ int cell_guess(float c) {
    float t = (c + 0.64f) * 200.0f;
    int i = (int)t;
    return min(max(i, 0), GRIDN - 1);
}

// exact jnp.searchsorted(p, c, side='left') + clip semantics
__device__ __forceinline__ void dim_interp(float c, const float* __restrict__ p,
                                           int& il, int& ir, float& dl, float& dr) {
    const float SCALE = 0.005f;
    const float OFFSET = -0.64f;
    float t = (c - OFFSET) * (1.0f / SCALE);
    int i = (int)ceilf(t);
    i = min(max(i, 0), GRIDN - 1);
    while (i < GRIDN - 1 && p[i] < c) ++i;
    while (i > 0 && p[i - 1] >= c) --i;
    ir = i;
    il = max(i - 1, 0);
    dl = fmaxf(c - p[il], 0.0f);
    dr = fmaxf(p[ir] - c, 0.0f);
    if (dl == 0.0f && dr == 0.0f) { dl = 1.0f; dr = 1.0f; }
}

// full interp, 8 scalar gathers (rare fallback paths only)
__device__ __forceinline__ float interp_point_ax(float cx, float cy, float cz,
                                                 const float* __restrict__ values,
                                                 const float* __restrict__ ax,
                                                 const float* __restrict__ ay,
                                                 const float* __restrict__ az) {
    int ixl, ixr, iyl, iyr, izl, izr;
    float dxl, dxr, dyl, dyr, dzl, dzr;
    dim_interp(cx, ax, ixl, ixr, dxl, dxr);
    dim_interp(cy, ay, iyl, iyr, dyl, dyr);
    dim_interp(cz, az, izl, izr, dzl, dzr);
    int bxl = ixl << 16, bxr = ixr << 16;
    int byl = iyl << 8,  byr = iyr << 8;
    float num =
        values[bxl + byl + izl] * (dxr * dyr * dzr) +
        values[bxl + byl + izr] * (dxr * dyr * dzl) +
        values[bxl + byr + izl] * (dxr * dyl * dzr) +
        values[bxl + byr + izr] * (dxr * dyl * dzl) +
        values[bxr + byl + izl] * (dxl * dyr * dzr) +
        values[bxr + byl + izr] * (dxl * dyr * dzl) +
        values[bxr + byr + izl] * (dxl * dyl * dzr) +
        values[bxr + byr + izr] * (dxl * dyl * dzl);
    float den = (dxl + dxr) * (dyl + dyr) * (dzl + dzr);
    return num / den;
}

// interp with z-pair dwordx2 gathers (4 memory ops). ir in {il, il+1};
// izl <= 254 so the float2 is in-bounds; select .x when izr==izl.
__device__ __forceinline__ float interp_zpair(float cx, float cy, float cz,
                                              const float* __restrict__ values,
                                              const float* __restrict__ sax) {
    int ixl, ixr, iyl, iyr, izl, izr;
    float dxl, dxr, dyl, dyr, dzl, dzr;
    dim_interp(cx, sax,             ixl, ixr, dxl, dxr);
    dim_interp(cy, sax + GRIDN,     iyl, iyr, dyl, dyr);
    dim_interp(cz, sax + 2 * GRIDN, izl, izr, dzl, dzr);

    int bxl = ixl << 16, bxr = ixr << 16;
    int byl = iyl << 8,  byr = iyr << 8;

    float2 vll, vlr, vrl, vrr;
    __builtin_memcpy(&vll, &values[bxl + byl + izl], 8);
    __builtin_memcpy(&vlr, &values[bxl + byr + izl], 8);
    __builtin_memcpy(&vrl, &values[bxr + byl + izl], 8);
    __builtin_memcpy(&vrr, &values[bxr + byr + izl], 8);

    bool zsame = (izr == izl);
    float zll = vll.x, zlr = zsame ? vll.x : vll.y;
    float yll = vlr.x, ylr = zsame ? vlr.x : vlr.y;
    float xll = vrl.x, xlr = zsame ? vrl.x : vrl.y;
    float wll = vrr.x, wlr = zsame ? vrr.x : vrr.y;

    float num =
        (dxr * dyr) * (zll * dzr + zlr * dzl) +
        (dxr * dyl) * (yll * dzr + ylr * dzl) +
        (dxl * dyr) * (xll * dzr + xlr * dzl) +
        (dxl * dyl) * (wll * dzr + wlr * dzl);
    float den = (dxl + dxr) * (dyl + dyr) * (dzl + dzr);
    return num / den;
}

__device__ __forceinline__ int bin_of_cells(int cgx, int cgy, int cgz) {
    // 8 x-bins (32 cells), 8 y-bins (32 cells), 16 z-bins (16 cells)
    return ((cgx >> 5) << 7) | ((cgy >> 5) << 4) | (cgz >> 4);
}

// ---------- K1: block-aggregated coarse bin scatter (cursors hold COUNTS) ----------

__global__ __launch_bounds__(1024) void bin_scatter2(
        const float* __restrict__ x, int K,
        unsigned* __restrict__ cursor,
        float4* __restrict__ records,
        int* __restrict__ inv,
        const float* __restrict__ values,
        const float* __restrict__ px,
        const float* __restrict__ py,
        const float* __restrict__ pz,
        float* __restrict__ out) {
    __shared__ unsigned cnt[NBINS];
    __shared__ unsigned slotcur[NBINS];

    int base = blockIdx.x * 4096;
    int end = min(base + 4096, K);

    for (int t = threadIdx.x; t < NBINS; t += 1024) cnt[t] = 0;
    __syncthreads();

    for (int i = base + threadIdx.x; i < end; i += 1024) {
        int b = bin_of_cells(cell_guess(x[3 * i]), cell_guess(x[3 * i + 1]),
                             cell_guess(x[3 * i + 2]));
        atomicAdd(&cnt[b], 1u);
    }
    __syncthreads();

    // cursor holds count; slot base = bin*CAP + old count
    for (int t = threadIdx.x; t < NBINS; t += 1024)
        slotcur[t] = cnt[t] ? ((unsigned)t * CAP +
                               atomicAdd(&cursor[t * CURSOR_STRIDE], cnt[t]))
                            : 0u;
    __syncthreads();

    for (int i = base + threadIdx.x; i < end; i += 1024) {
        float cx = x[3 * i], cy = x[3 * i + 1], cz = x[3 * i + 2];
        int b = bin_of_cells(cell_guess(cx), cell_guess(cy), cell_guess(cz));
        unsigned s = atomicAdd(&slotcur[b], 1u);
        if (s < (unsigned)((b + 1) * CAP)) {
            records[s] = make_float4(cx, cy, cz, 0.0f);
            inv[i] = (int)s;
        } else {
            inv[i] = -1;   // overflow (statistically never): compute inline
            out[i] = interp_point_ax(cx, cy, cz, values, px, py, pz);
        }
    }
}

// ---------- K2: one 1024-thr block per bin; 256-key fine z-sort; 2 blocks/CU ----------

#define K2_THREADS 1024

__global__ __launch_bounds__(K2_THREADS) void interp_binsort(
        const float4* __restrict__ records,
        const unsigned* __restrict__ cursor,
        const float* __restrict__ values,
        const float* __restrict__ px,
        const float* __restrict__ py,
        const float* __restrict__ pz,
        float* __restrict__ res) {
    __shared__ float sax[3 * GRIDN];            // 3 KB
    __shared__ unsigned hist[FKEYS];            // 1 KB
    __shared__ unsigned wsum[4];
    __shared__ unsigned char skeys[CAP];        // 3 KB
    __shared__ unsigned short order[CAP];       // 6 KB
    __shared__ float sx[CAP], sy[CAP], sz[CAP]; // 36 KB
    __shared__ float sres[CAP];                 // 12 KB   (total ~61 KB -> 2 blocks/CU)

    // bijective XCD swizzle: consecutive bins (z-adjacent) on one XCD
    int nb = gridDim.x;               // 1024, divisible by 8
    int b = blockIdx.x;
    int q = nb >> 3;
    int bin = (b & 7) * q + (b >> 3);

    for (int t = threadIdx.x; t < GRIDN; t += K2_THREADS) {
        sax[t] = px[t];
        sax[GRIDN + t] = py[t];
        sax[2 * GRIDN + t] = pz[t];
    }
    if (threadIdx.x < FKEYS) hist[threadIdx.x] = 0;
    __syncthreads();

    unsigned binstart = (unsigned)bin * CAP;
    int npts = min((int)cursor[bin * CURSOR_STRIDE], CAP);
    if (npts <= 0) return;

    int cbx = (bin >> 7) << 5;
    int cby = ((bin >> 4) & 7) << 5;
    int cbz = (bin & 15) << 4;

    // phase 1: one coalesced read of the bin's records -> LDS; fine key + hist
    for (int pt = threadIdx.x; pt < npts; pt += K2_THREADS) {
        float4 rec = records[binstart + pt];
        sx[pt] = rec.x; sy[pt] = rec.y; sz[pt] = rec.z;
        int fx = (cell_guess(rec.x) - cbx) >> 2;
        int fy = (cell_guess(rec.y) - cby) >> 2;
        int fz = (cell_guess(rec.z) - cbz) >> 2;
        fx = min(max(fx, 0), 7); fy = min(max(fy, 0), 7); fz = min(max(fz, 0), 3);
        int k = (((fx << 3) | fy) << 2) | fz;   // z fastest -> sorted order z-local
        skeys[pt] = (unsigned char)k;
        atomicAdd(&hist[k], 1u);
    }
    __syncthreads();

    // phase 2: hierarchical exclusive scan of 256 counts (3 barriers)
    unsigned v = 0, s = 0;
    int lane = threadIdx.x & 63, w = threadIdx.x >> 6;
    if (threadIdx.x < FKEYS) {
        v = hist[threadIdx.x];
        s = v;
        for (int off = 1; off < 64; off <<= 1) {
            unsigned t = __shfl_up(s, off, 64);
            if (lane >= off) s += t;
        }
        if (lane == 63) wsum[w] = s;    // wave-chunk total (inclusive)
    }
    __syncthreads();
    if (threadIdx.x == 0) {
        unsigned a = 0;
        for (int i = 0; i < 4; ++i) { unsigned t = wsum[i]; wsum[i] = a; a += t; }
    }
    __syncthreads();
    if (threadIdx.x < FKEYS) hist[threadIdx.x] = s - v + wsum[w];   // exclusive
    __syncthreads();

    // phase 3: scatter point indices into fine-sorted order
    for (int pt = threadIdx.x; pt < npts; pt += K2_THREADS) {
        unsigned slot = atomicAdd(&hist[skeys[pt]], 1u);
        order[slot] = (unsigned short)pt;
    }
    __syncthreads();

    // phase 4: process in z-sorted order; point data from LDS; z-pair gathers
    for (int pt = threadIdx.x; pt < npts; pt += K2_THREADS) {
        int j = order[pt];
        sres[j] = interp_zpair(sx[j], sy[j], sz[j], values, sax);
    }
    __syncthreads();

    // phase 5: dense coalesced writeout
    for (int pt = threadIdx.x; pt < npts; pt += K2_THREADS)
        res[binstart + pt] = sres[pt];
}

// ---------- K3: unscatter results to original order ----------

__global__ void unscatter(const int* __restrict__ inv,
                          const float* __restrict__ res,
                          float* __restrict__ out, int K) {
    int i = blockIdx.x * blockDim.x + threadIdx.x;
    if (i >= K) return;
    int s = inv[i];
    if (s >= 0) out[i] = res[s];
}

// ---------- fallback: direct (round-1) kernel ----------

__global__ void trilerp_direct(const float* __restrict__ x,
                               const float* __restrict__ values,
                               const float* __restrict__ px,
                               const float* __restrict__ py,
                               const float* __restrict__ pz,
                               float* __restrict__ out, int K) {
    int i = blockIdx.x * blockDim.x + threadIdx.x;
    if (i >= K) return;
    out[i] = interp_point_ax(x[3 * i], x[3 * i + 1], x[3 * i + 2],
                             values, px, py, pz);
}

extern "C" void kernel_launch(void* const* d_in, const int* in_sizes, int n_in,
                              void* d_out, int out_size, void* d_ws, size_t ws_size,
                              hipStream_t stream) {
    const float* x      = (const float*)d_in[0];
    const float* values = (const float*)d_in[1];
    const float* px     = (const float*)d_in[2];
    const float* py     = (const float*)d_in[3];
    const float* pz     = (const float*)d_in[4];
    float* out = (float*)d_out;

    int K = in_sizes[0] / 3;

    size_t cursor_bytes  = (size_t)NBINS * CURSOR_STRIDE * 4;   // 64 KB
    size_t records_bytes = (size_t)NBINS * CAP * 16;            // 50.3 MB
    size_t inv_bytes     = (size_t)K * 4;                       // 8 MB
    size_t res_bytes     = (size_t)NBINS * CAP * 4;             // 12.6 MB
    size_t need = cursor_bytes + records_bytes + inv_bytes + res_bytes;

    if (ws_size < need) {
        int grid = (K + 255) / 256;
        trilerp_direct<<<grid, 256, 0, stream>>>(x, values, px, py, pz, out, K);
        return;
    }

    char* p = (char*)d_ws;
    unsigned* cursor = (unsigned*)p;  p += cursor_bytes;
    float4* records  = (float4*)p;    p += records_bytes;
    int* inv         = (int*)p;       p += inv_bytes;
    float* res       = (float*)p;

    // cursors hold per-bin COUNTS now -> plain zero init
    hipMemsetAsync(cursor, 0, cursor_bytes, stream);

    int nblk1 = (K + 4095) / 4096;
    bin_scatter2<<<nblk1, 1024, 0, stream>>>(x, K, cursor, records, inv,
                                             values, px, py, pz, out);

    interp_binsort<<<NBINS, K2_THREADS, 0, stream>>>(records, cursor,
                                                     values, px, py, pz, res);

    int nblk3 = (K + 255) / 256;
    unscatter<<<nblk3, 256, 0, stream>>>(inv, res, out, K);
}

// Round 11
// 82.355 us; speedup vs baseline: 1.1562x; 1.1562x over previous
//
#include <hip/hip_runtime.h>

#define GRIDN 256
#define BPA 8                     // coarse bins per axis (32 cells each)
#define NBINS (BPA * BPA * BPA)   // 512
#define CAP 6144                  // slots per coarse bin (interior mean 4741, sigma 69)
#define HALF 2                    // K2 blocks per bin (slot-range split)
#define CAPH (CAP / HALF)         // 3072 pts per K2 block
#define CURSOR_STRIDE 16          // one cursor per 64B line
#define FKEYS 512                 // fine keys: 8x8x8 sub-bins of 4x4x4 cells, z fastest

// ---------- shared helpers ----------

__device__ __forceinline__ int cell_guess(float c) {
    float t = (c + 0.64f) * 200.0f;
    int i = (int)t;
    return min(max(i, 0), GRIDN - 1);
}

// exact jnp.searchsorted(p, c, side='left') + clip semantics
__device__ __forceinline__ void dim_interp(float c, const float* __restrict__ p,
                                           int& il, int& ir, float& dl, float& dr) {
    const float SCALE = 0.005f;
    const float OFFSET = -0.64f;
    float t = (c - OFFSET) * (1.0f / SCALE);
    int i = (int)ceilf(t);
    i = min(max(i, 0), GRIDN - 1);
    while (i < GRIDN - 1 && p[i] < c) ++i;
    while (i > 0 && p[i - 1] >= c) --i;
    ir = i;
    il = max(i - 1, 0);
    dl = fmaxf(c - p[il], 0.0f);
    dr = fmaxf(p[ir] - c, 0.0f);
    if (dl == 0.0f && dr == 0.0f) { dl = 1.0f; dr = 1.0f; }
}

// full interp, 8 scalar gathers (rare fallback paths only)
__device__ __forceinline__ float interp_point_ax(float cx, float cy, float cz,
                                                 const float* __restrict__ values,
                                                 const float* __restrict__ ax,
                                                 const float* __restrict__ ay,
                                                 const float* __restrict__ az) {
    int ixl, ixr, iyl, iyr, izl, izr;
    float dxl, dxr, dyl, dyr, dzl, dzr;
    dim_interp(cx, ax, ixl, ixr, dxl, dxr);
    dim_interp(cy, ay, iyl, iyr, dyl, dyr);
    dim_interp(cz, az, izl, izr, dzl, dzr);
    int bxl = ixl << 16, bxr = ixr << 16;
    int byl = iyl << 8,  byr = iyr << 8;
    float num =
        values[bxl + byl + izl] * (dxr * dyr * dzr) +
        values[bxl + byl + izr] * (dxr * dyr * dzl) +
        values[bxl + byr + izl] * (dxr * dyl * dzr) +
        values[bxl + byr + izr] * (dxr * dyl * dzl) +
        values[bxr + byl + izl] * (dxl * dyr * dzr) +
        values[bxr + byl + izr] * (dxl * dyr * dzl) +
        values[bxr + byr + izl] * (dxl * dyl * dzr) +
        values[bxr + byr + izr] * (dxl * dyl * dzl);
    float den = (dxl + dxr) * (dyl + dyr) * (dzl + dzr);
    return num / den;
}

// interp with z-pair dwordx2 gathers (4 memory ops). ir in {il, il+1};
// izl <= 254 so the float2 is in-bounds; select .x when izr==izl.
__device__ __forceinline__ float interp_zpair(float cx, float cy, float cz,
                                              const float* __restrict__ values,
                                              const float* __restrict__ sax) {
    int ixl, ixr, iyl, iyr, izl, izr;
    float dxl, dxr, dyl, dyr, dzl, dzr;
    dim_interp(cx, sax,             ixl, ixr, dxl, dxr);
    dim_interp(cy, sax + GRIDN,     iyl, iyr, dyl, dyr);
    dim_interp(cz, sax + 2 * GRIDN, izl, izr, dzl, dzr);

    int bxl = ixl << 16, bxr = ixr << 16;
    int byl = iyl << 8,  byr = iyr << 8;

    float2 vll, vlr, vrl, vrr;
    __builtin_memcpy(&vll, &values[bxl + byl + izl], 8);
    __builtin_memcpy(&vlr, &values[bxl + byr + izl], 8);
    __builtin_memcpy(&vrl, &values[bxr + byl + izl], 8);
    __builtin_memcpy(&vrr, &values[bxr + byr + izl], 8);

    bool zsame = (izr == izl);
    float zll = vll.x, zlr = zsame ? vll.x : vll.y;
    float yll = vlr.x, ylr = zsame ? vlr.x : vlr.y;
    float xll = vrl.x, xlr = zsame ? vrl.x : vrl.y;
    float wll = vrr.x, wlr = zsame ? vrr.x : vrr.y;

    float num =
        (dxr * dyr) * (zll * dzr + zlr * dzl) +
        (dxr * dyl) * (yll * dzr + ylr * dzl) +
        (dxl * dyr) * (xll * dzr + xlr * dzl) +
        (dxl * dyl) * (wll * dzr + wlr * dzl);
    float den = (dxl + dxr) * (dyl + dyr) * (dzl + dzr);
    return num / den;
}

// ---------- K1: block-aggregated coarse bin scatter (512 bins, proven) ----------

__global__ __launch_bounds__(1024) void bin_scatter2(
        const float* __restrict__ x, int K,
        unsigned* __restrict__ cursor,     // holds per-bin COUNTS (zero-init)
        float4* __restrict__ records,
        int* __restrict__ inv,
        const float* __restrict__ values,
        const float* __restrict__ px,
        const float* __restrict__ py,
        const float* __restrict__ pz,
        float* __restrict__ out) {
    __shared__ unsigned cnt[NBINS];
    __shared__ unsigned slotcur[NBINS];

    int base = blockIdx.x * 4096;
    int end = min(base + 4096, K);

    for (int t = threadIdx.x; t < NBINS; t += 1024) cnt[t] = 0;
    __syncthreads();

    for (int i = base + threadIdx.x; i < end; i += 1024) {
        int bx = cell_guess(x[3 * i]) >> 5;
        int by = cell_guess(x[3 * i + 1]) >> 5;
        int bz = cell_guess(x[3 * i + 2]) >> 5;
        atomicAdd(&cnt[(bx * BPA + by) * BPA + bz], 1u);
    }
    __syncthreads();

    for (int t = threadIdx.x; t < NBINS; t += 1024)
        slotcur[t] = cnt[t] ? ((unsigned)t * CAP +
                               atomicAdd(&cursor[t * CURSOR_STRIDE], cnt[t]))
                            : 0u;
    __syncthreads();

    for (int i = base + threadIdx.x; i < end; i += 1024) {
        float cx = x[3 * i], cy = x[3 * i + 1], cz = x[3 * i + 2];
        int bx = cell_guess(cx) >> 5;
        int by = cell_guess(cy) >> 5;
        int bz = cell_guess(cz) >> 5;
        int b = (bx * BPA + by) * BPA + bz;
        unsigned s = atomicAdd(&slotcur[b], 1u);
        if (s < (unsigned)((b + 1) * CAP)) {
            records[s] = make_float4(cx, cy, cz, 0.0f);
            inv[i] = (int)s;
        } else {
            inv[i] = -1;   // overflow (statistically never): compute inline
            out[i] = interp_point_ax(cx, cy, cz, values, px, py, pz);
        }
    }
}

// ---------- K2: 2 blocks per coarse bin (slot-split); 512-key fine z-sort ----------

#define K2_THREADS 1024

__global__ __launch_bounds__(K2_THREADS) void interp_halfsort(
        const float4* __restrict__ records,
        const unsigned* __restrict__ cursor,
        const float* __restrict__ values,
        const float* __restrict__ px,
        const float* __restrict__ py,
        const float* __restrict__ pz,
        float* __restrict__ res) {
    __shared__ float sax[3 * GRIDN];              // 3 KB
    __shared__ unsigned hist[FKEYS];              // 2 KB
    __shared__ unsigned wsum[8];
    __shared__ unsigned short skeys[CAPH];        // 6 KB
    __shared__ unsigned short order[CAPH];        // 6 KB
    __shared__ float sx[CAPH], sy[CAPH], sz[CAPH]; // 36 KB
    __shared__ float sres[CAPH];                  // 12 KB  (total ~65 KB -> 2/CU)

    // bijective XCD swizzle; lin consecutive -> same XCD, halves of a bin adjacent
    int nb = gridDim.x;               // 1024, divisible by 8
    int b = blockIdx.x;
    int q = nb >> 3;
    int lin = (b & 7) * q + (b >> 3);
    int bin = lin >> 1;
    int half = lin & 1;

    for (int t = threadIdx.x; t < GRIDN; t += K2_THREADS) {
        sax[t] = px[t];
        sax[GRIDN + t] = py[t];
        sax[2 * GRIDN + t] = pz[t];
    }
    for (int t = threadIdx.x; t < FKEYS; t += K2_THREADS) hist[t] = 0;
    __syncthreads();

    unsigned binstart = (unsigned)bin * CAP;
    int npts = min((int)cursor[bin * CURSOR_STRIDE], CAP);
    if (npts <= 0) return;

    int cnt_h = (npts + HALF - 1) / HALF;      // <= CAPH
    int lo = half * cnt_h;
    int n = min(npts, lo + cnt_h) - lo;
    if (n <= 0) return;
    unsigned base = binstart + lo;

    int cbx = (bin >> 6) << 5;
    int cby = ((bin >> 3) & 7) << 5;
    int cbz = (bin & 7) << 5;

    // phase 1: coalesced read of the half's records -> LDS; 4^3-cell key + hist
    for (int pt = threadIdx.x; pt < n; pt += K2_THREADS) {
        float4 rec = records[base + pt];
        sx[pt] = rec.x; sy[pt] = rec.y; sz[pt] = rec.z;
        int fx = (cell_guess(rec.x) - cbx) >> 2;
        int fy = (cell_guess(rec.y) - cby) >> 2;
        int fz = (cell_guess(rec.z) - cbz) >> 2;
        fx = min(max(fx, 0), 7); fy = min(max(fy, 0), 7); fz = min(max(fz, 0), 7);
        int k = (((fx << 3) | fy) << 3) | fz;   // z fastest -> sorted order z-local
        skeys[pt] = (unsigned short)k;
        atomicAdd(&hist[k], 1u);
    }
    __syncthreads();

    // phase 2: hierarchical exclusive scan of 512 counts (3 barriers)
    unsigned v = 0, s = 0;
    int lane = threadIdx.x & 63, w = threadIdx.x >> 6;
    if (threadIdx.x < FKEYS) {
        v = hist[threadIdx.x];
        s = v;
        for (int off = 1; off < 64; off <<= 1) {
            unsigned t = __shfl_up(s, off, 64);
            if (lane >= off) s += t;
        }
        if (lane == 63) wsum[w] = s;    // wave-chunk inclusive total
    }
    __syncthreads();
    if (threadIdx.x == 0) {
        unsigned a = 0;
        for (int i = 0; i < 8; ++i) { unsigned t = wsum[i]; wsum[i] = a; a += t; }
    }
    __syncthreads();
    if (threadIdx.x < FKEYS) hist[threadIdx.x] = s - v + wsum[w];   // exclusive
    __syncthreads();

    // phase 3: scatter point indices into fine-sorted order
    for (int pt = threadIdx.x; pt < n; pt += K2_THREADS) {
        unsigned slot = atomicAdd(&hist[skeys[pt]], 1u);
        order[slot] = (unsigned short)pt;
    }
    __syncthreads();

    // phase 4: process in z-sorted order; point data from LDS; z-pair gathers
    for (int pt = threadIdx.x; pt < n; pt += K2_THREADS) {
        int j = order[pt];
        sres[j] = interp_zpair(sx[j], sy[j], sz[j], values, sax);
    }
    __syncthreads();

    // phase 5: dense coalesced writeout
    for (int pt = threadIdx.x; pt < n; pt += K2_THREADS)
        res[base + pt] = sres[pt];
}

// ---------- K3: unscatter results to original order ----------

__global__ void unscatter(const int* __restrict__ inv,
                          const float* __restrict__ res,
                          float* __restrict__ out, int K) {
    int i = blockIdx.x * blockDim.x + threadIdx.x;
    if (i >= K) return;
    int s = inv[i];
    if (s >= 0) out[i] = res[s];
}

// ---------- fallback: direct (round-1) kernel ----------

__global__ void trilerp_direct(const float* __restrict__ x,
                               const float* __restrict__ values,
                               const float* __restrict__ px,
                               const float* __restrict__ py,
                               const float* __restrict__ pz,
                               float* __restrict__ out, int K) {
    int i = blockIdx.x * blockDim.x + threadIdx.x;
    if (i >= K) return;
    out[i] = interp_point_ax(x[3 * i], x[3 * i + 1], x[3 * i + 2],
                             values, px, py, pz);
}

extern "C" void kernel_launch(void* const* d_in, const int* in_sizes, int n_in,
                              void* d_out, int out_size, void* d_ws, size_t ws_size,
                              hipStream_t stream) {
    const float* x      = (const float*)d_in[0];
    const float* values = (const float*)d_in[1];
    const float* px     = (const float*)d_in[2];
    const float* py     = (const float*)d_in[3];
    const float* pz     = (const float*)d_in[4];
    float* out = (float*)d_out;

    int K = in_sizes[0] / 3;

    size_t cursor_bytes  = (size_t)NBINS * CURSOR_STRIDE * 4;   // 32 KB
    size_t records_bytes = (size_t)NBINS * CAP * 16;            // 50.3 MB
    size_t inv_bytes     = (size_t)K * 4;                       // 8 MB
    size_t res_bytes     = (size_t)NBINS * CAP * 4;             // 12.6 MB
    size_t need = cursor_bytes + records_bytes + inv_bytes + res_bytes;

    if (ws_size < need) {
        int grid = (K + 255) / 256;
        trilerp_direct<<<grid, 256, 0, stream>>>(x, values, px, py, pz, out, K);
        return;
    }

    char* p = (char*)d_ws;
    unsigned* cursor = (unsigned*)p;  p += cursor_bytes;
    float4* records  = (float4*)p;    p += records_bytes;
    int* inv         = (int*)p;       p += inv_bytes;
    float* res       = (float*)p;

    hipMemsetAsync(cursor, 0, cursor_bytes, stream);

    int nblk1 = (K + 4095) / 4096;
    bin_scatter2<<<nblk1, 1024, 0, stream>>>(x, K, cursor, records, inv,
                                             values, px, py, pz, out);

    interp_halfsort<<<NBINS * HALF, K2_THREADS, 0, stream>>>(records, cursor,
                                                             values, px, py, pz, res);

    int nblk3 = (K + 255) / 256;
    unscatter<<<nblk3, 256, 0, stream>>>(inv, res, out, K);
}